// Round 3
// baseline (124.417 us; speedup 1.0000x reference)
//
#include <hip/hip_runtime.h>

#define NB   2
#define SKV  1024
#define NSQ  512
#define HIN  256
#define HA   128

// projections pre-scaled by 2*log2(e):  exp2(KSC*x) = e^{2x}
// tanh(x) = 1 - 2/(e^{2x}+1); softmax is shift-invariant so the constant
// W0+bv terms of the score are dropped entirely.
#define KSC   2.8853900817779268f   // 2*log2(e)

// ---------------- Kernel A: projections -> exponentials ----------------
// Rows are WAVE-uniform (readfirstlane-forced) -> s_load path, no LDS.
// kv rows -> ekT interleaved-transposed ekT[b][a>>2][s][a&3]; q rows -> eq
// row-major.  W loads are coalesced b32 (256 B/wave), L2-hot.
__global__ __launch_bounds__(512) void proj_kernel(
    const float* __restrict__ kv,
    const float* __restrict__ qy,
    const float* __restrict__ Wkv,
    const float* __restrict__ bkv,
    const float* __restrict__ Wq,
    const float* __restrict__ bq,
    float* __restrict__ ekT,
    float* __restrict__ eq)
{
    const int t  = threadIdx.x;
    const int a  = t & 127;                       // output channel
    const int rh = __builtin_amdgcn_readfirstlane(t >> 7);   // wave-uniform 0..3
    const int r0 = blockIdx.x * 8;                // 8 rows per block
    const bool is_q = (r0 >= NB * SKV);
    const float* __restrict__ base = is_q ? (qy + (size_t)(r0 - NB * SKV) * HIN)
                                          : (kv + (size_t)r0 * HIN);
    const float* __restrict__ W  = is_q ? Wq : Wkv;
    const float* __restrict__ bs = is_q ? bq : bkv;

    // two rows per thread, both wave-uniform -> s_load_dwordx4
    const float4* __restrict__ rowA = (const float4*)(base + (size_t)(rh * 2) * HIN);
    const float4* __restrict__ rowB = (const float4*)(base + (size_t)(rh * 2 + 1) * HIN);

    float a0 = 0.f, a1 = 0.f;
    #pragma unroll 4
    for (int h4 = 0; h4 < 64; ++h4) {
        const float4 rA = rowA[h4];               // scalar (uniform) loads
        const float4 rB = rowB[h4];
        #pragma unroll
        for (int j = 0; j < 4; ++j) {
            const float w = W[(size_t)(h4 * 4 + j) * HA + a];   // coalesced b32
            a0 = fmaf(((const float*)&rA)[j], w, a0);
            a1 = fmaf(((const float*)&rB)[j], w, a1);
        }
    }
    const float bb = bs[a];
    const float e0 = __builtin_amdgcn_exp2f((a0 + bb) * KSC);
    const float e1 = __builtin_amdgcn_exp2f((a1 + bb) * KSC);
    const int ra = rh * 2, rb = rh * 2 + 1;
    if (is_q) {
        const int r = r0 - NB * SKV;
        eq[(size_t)(r + ra) * HA + a] = e0;
        eq[(size_t)(r + rb) * HA + a] = e1;
    } else {
        const int bI = r0 >> 10, s0 = r0 & 1023;
        float* __restrict__ p =
            ekT + ((size_t)(bI * 32 + (a >> 2)) * SKV + s0) * 4 + (a & 3);
        p[(size_t)ra * 4] = e0;
        p[(size_t)rb * 4] = e1;
    }
}

// ---------------- Kernel B: scores + softmax + weight write ----------------
// one block = 4 consecutive (b,q) rows; 1024 threads; grid 256; thread = one s.
// score(q,s) (shifted) = -2 * sum_a wv_a / (Ek[s][a]*Eq[q][a] + 1)
// Q and wv are block-uniform -> s_load into SGPRs; E is the only vector
// traffic (coalesced b128 via the ekT interleave).  No LDS in the hot loop.
__global__ __launch_bounds__(1024) void attn_kernel(
    const float* __restrict__ ekT,         // interleaved-transposed exps
    const float* __restrict__ eq,          // (1024,128) exps, row-major
    const float* __restrict__ wv,          // (128)
    float* __restrict__ out)               // [262144 out0][1048576 weights]
{
    __shared__ float red[2][4][16];

    const int tid  = threadIdx.x;
    const int lane = tid & 63, wid = tid >> 6;
    const int bq0  = blockIdx.x * 4;       // never straddles b (512%4==0)
    const int b    = bq0 >> 9;

    // block-uniform bases -> scalar loads
    const float4* __restrict__ Q0p = (const float4*)(eq + (size_t)(bq0 + 0) * HA);
    const float4* __restrict__ Q1p = (const float4*)(eq + (size_t)(bq0 + 1) * HA);
    const float4* __restrict__ Q2p = (const float4*)(eq + (size_t)(bq0 + 2) * HA);
    const float4* __restrict__ Q3p = (const float4*)(eq + (size_t)(bq0 + 3) * HA);
    const float4* __restrict__ wv4 = (const float4*)wv;

    // ---- phase 2: per-thread s, 4 q accumulators; paired rcp over a ----
    const float4* __restrict__ E4 =
        (const float4*)ekT + (size_t)b * 32 * SKV + tid;   // + a4*SKV per iter
    float t0 = 0.f, t1 = 0.f, t2 = 0.f, t3 = 0.f;

    #pragma unroll 8
    for (int a4 = 0; a4 < 32; ++a4) {
        const float4 E = E4[(size_t)a4 * SKV];             // coalesced b128
        const float4 w  = wv4[a4];                         // SGPR
        const float4 Q0 = Q0p[a4];                         // SGPR
        const float4 Q1 = Q1p[a4];
        const float4 Q2 = Q2p[a4];
        const float4 Q3 = Q3p[a4];

#define PQ(ACC, Q)                                                            \
        {                                                                     \
            float u  = fmaf(E.x, Q.x, 1.f);                                   \
            float v  = fmaf(E.y, Q.y, 1.f);                                   \
            ACC = fmaf(fmaf(w.x, v, w.y * u),                                 \
                       __builtin_amdgcn_rcpf(u * v), ACC);                    \
            float u2 = fmaf(E.z, Q.z, 1.f);                                   \
            float v2 = fmaf(E.w, Q.w, 1.f);                                   \
            ACC = fmaf(fmaf(w.z, v2, w.w * u2),                               \
                       __builtin_amdgcn_rcpf(u2 * v2), ACC);                  \
        }
        PQ(t0, Q0) PQ(t1, Q1) PQ(t2, Q2) PQ(t3, Q3)
#undef PQ
    }

    // ---- phase 3: softmax over s.  weight ∝ exp(-2*(t - tmin)) ----
    float tq[4] = {t0, t1, t2, t3};
    #pragma unroll
    for (int q = 0; q < 4; ++q) {
        float m = tq[q];
        #pragma unroll
        for (int o = 32; o > 0; o >>= 1) m = fminf(m, __shfl_down(m, o));
        if (lane == 0) red[0][q][wid] = m;
    }
    __syncthreads();
    float M[4];
    #pragma unroll
    for (int q = 0; q < 4; ++q) {
        float m = red[0][q][0];
        #pragma unroll
        for (int i = 1; i < 16; ++i) m = fminf(m, red[0][q][i]);
        M[q] = m;
    }
    float e[4];
    #pragma unroll
    for (int q = 0; q < 4; ++q) {
        e[q] = __builtin_amdgcn_exp2f((M[q] - tq[q]) * KSC);   // exp(-2(t-tmin))
        float sum = e[q];
        #pragma unroll
        for (int o = 32; o > 0; o >>= 1) sum += __shfl_down(sum, o);
        if (lane == 0) red[1][q][wid] = sum;
    }
    __syncthreads();
    float* __restrict__ outw = out + (size_t)NB * NSQ * HIN;   // weights at 262144
    #pragma unroll
    for (int q = 0; q < 4; ++q) {
        float d = red[1][q][0];
        #pragma unroll
        for (int i = 1; i < 16; ++i) d += red[1][q][i];
        outw[(size_t)(bq0 + q) * SKV + tid] = e[q] * __builtin_amdgcn_rcpf(d);
    }
}

// ---------------- Kernel C: out0 = weights @ kv ----------------
// block = (4-q group) x (h-half of 128); grid 512 (2 blocks/CU).
// Weights staged q-major wtT[4][1024]: one b128 read = 4 s-weights of one q
// -> 16 wt-reads/thread (vs 64 broadcasts).  2-round shfl partial reduce.
__global__ __launch_bounds__(1024) void out_kernel(
    const float* __restrict__ kv,          // (2048,256)
    const float* __restrict__ outw,        // (1024,1024) weights (just written)
    float* __restrict__ out)               // out0 (1024,256)
{
    __shared__ __align__(16) float wtT[4][SKV];        // 16 KB, q-major
    __shared__ __align__(16) float part[16][4][HA];    // 32 KB

    const int t  = threadIdx.x;
    const int lane = t & 63, wid = t >> 6;
    const int qg = blockIdx.x >> 1, hh = blockIdx.x & 1;
    const int b  = qg >> 7;                // 128 q-groups per batch

    // stage 4 q-rows of weights, q-major (coalesced read, conflict-free write)
    #pragma unroll
    for (int j = 0; j < 4; ++j) {
        const int idx = j * 1024 + t, q = idx >> 10, s = idx & 1023;
        wtT[q][s] = outw[(size_t)(qg * 4 + q) * SKV + s];
    }
    __syncthreads();

    const int hg = t & 15, sg = t >> 4;    // 16 h-groups(8h) x 64 s-groups(16s)
    const float* __restrict__ kvb =
        kv + ((size_t)(b * SKV + sg * 16)) * HIN + hh * HA + hg * 8;

    float4 acA[4], acB[4];
    #pragma unroll
    for (int q = 0; q < 4; ++q) { acA[q] = make_float4(0,0,0,0); acB[q] = make_float4(0,0,0,0); }

    #pragma unroll
    for (int qd = 0; qd < 4; ++qd) {       // 4 s-quads of 4
        const int s0 = sg * 16 + qd * 4;
        float4 w4[4];
        #pragma unroll
        for (int q = 0; q < 4; ++q) w4[q] = *(const float4*)&wtT[q][s0];  // b128
        #pragma unroll
        for (int i = 0; i < 4; ++i) {
            const float* kr = kvb + (size_t)(qd * 4 + i) * HIN;
            const float4 vA = *(const float4*)kr;
            const float4 vB = *(const float4*)(kr + 4);
            #pragma unroll
            for (int q = 0; q < 4; ++q) {
                const float ww = ((const float*)&w4[q])[i];
                acA[q].x = fmaf(ww, vA.x, acA[q].x); acA[q].y = fmaf(ww, vA.y, acA[q].y);
                acA[q].z = fmaf(ww, vA.z, acA[q].z); acA[q].w = fmaf(ww, vA.w, acA[q].w);
                acB[q].x = fmaf(ww, vB.x, acB[q].x); acB[q].y = fmaf(ww, vB.y, acB[q].y);
                acB[q].z = fmaf(ww, vB.z, acB[q].z); acB[q].w = fmaf(ww, vB.w, acB[q].w);
            }
        }
    }

    // reduce 4 s-subgroups within wave (lanes 16 apart share hg)
    #pragma unroll
    for (int q = 0; q < 4; ++q) {
        #pragma unroll
        for (int c = 0; c < 4; ++c) {
            float xA = ((float*)&acA[q])[c], xB = ((float*)&acB[q])[c];
            xA += __shfl_down(xA, 16); xA += __shfl_down(xA, 32);
            xB += __shfl_down(xB, 16); xB += __shfl_down(xB, 32);
            ((float*)&acA[q])[c] = xA; ((float*)&acB[q])[c] = xB;
        }
    }
    if (lane < 16) {
        #pragma unroll
        for (int q = 0; q < 4; ++q) {
            *(float4*)&part[wid][q][hg * 8]     = acA[q];
            *(float4*)&part[wid][q][hg * 8 + 4] = acB[q];
        }
    }
    __syncthreads();

    if (t < 512) {
        const int q = t >> 7, h = t & 127;
        float v = 0.f;
        #pragma unroll
        for (int g = 0; g < 16; ++g) v += part[g][q][h];   // stride-1 banks
        out[(size_t)(qg * 4 + q) * HIN + hh * HA + h] = v; // coalesced
    }
}

extern "C" void kernel_launch(void* const* d_in, const int* in_sizes, int n_in,
                              void* d_out, int out_size, void* d_ws, size_t ws_size,
                              hipStream_t stream) {
    (void)in_sizes; (void)n_in; (void)out_size; (void)ws_size;
    const float* kv  = (const float*)d_in[0];
    const float* qy  = (const float*)d_in[1];
    const float* Wkv = (const float*)d_in[2];
    const float* bkv = (const float*)d_in[3];
    const float* Wq  = (const float*)d_in[4];
    const float* bq  = (const float*)d_in[5];
    const float* wv  = (const float*)d_in[6];
    float* ekT = (float*)d_ws;                 // 1 MB
    float* eqp = ekT + (size_t)NB * SKV * HA;  // 0.5 MB
    float* out = (float*)d_out;
    float* outw = out + (size_t)NB * NSQ * HIN;

    hipLaunchKernelGGL(proj_kernel, dim3((NB * SKV + NB * NSQ) / 8), dim3(512), 0, stream,
                       kv, qy, Wkv, bkv, Wq, bq, ekT, eqp);
    hipLaunchKernelGGL(attn_kernel, dim3(NB * NSQ / 4), dim3(1024), 0, stream,
                       ekT, eqp, wv, out);
    hipLaunchKernelGGL(out_kernel, dim3(NB * NSQ / 2), dim3(1024), 0, stream,
                       kv, outw, out);
}

// Round 5
// 118.090 us; speedup vs baseline: 1.0536x; 1.0536x over previous
//
#include <hip/hip_runtime.h>

#define NB   2
#define SKV  1024
#define NSQ  512
#define HIN  256
#define HA   128

// projections pre-scaled by 2*log2(e):  exp2(KSC*x) = e^{2x}
// tanh(x) = 1 - 2/(e^{2x}+1); softmax is shift-invariant so the constant
// W0+bv terms of the score are dropped entirely.
#define KSC   2.8853900817779268f   // 2*log2(e)

// ---------------- Kernel A: projections -> exponentials ----------------
// (R2 version, unchanged — part of the best measured build.)
// kv rows -> ekT, INTERLEAVED-TRANSPOSED: ekT[b][a>>2][s][a&3]; q rows -> eq
// row-major [r][a].
__global__ __launch_bounds__(512) void proj_kernel(
    const float* __restrict__ kv,
    const float* __restrict__ qy,
    const float* __restrict__ Wkv,
    const float* __restrict__ bkv,
    const float* __restrict__ Wq,
    const float* __restrict__ bq,
    float* __restrict__ ekT,
    float* __restrict__ eq)
{
    __shared__ __align__(16) float rowf[8][HIN];
    const int t  = threadIdx.x;
    const int a  = t & 127;            // output channel
    const int rh = t >> 7;             // row-pair id (0..3)
    const int r0 = blockIdx.x * 8;     // 8 rows per block
    const bool is_q = (r0 >= NB * SKV);
    const float* __restrict__ src = is_q ? (qy + (size_t)(r0 - NB * SKV) * HIN)
                                         : (kv + (size_t)r0 * HIN);
    const float* __restrict__ W  = is_q ? Wq : Wkv;
    const float* __restrict__ bs = is_q ? bq : bkv;

    ((float4*)rowf)[t] = ((const float4*)src)[t];
    __syncthreads();

    float a0 = 0.f, a1 = 0.f;
    const int ra = rh * 2, rb = rh * 2 + 1;
    #pragma unroll 4
    for (int h4 = 0; h4 < 64; ++h4) {
        const float4 r4a = ((const float4*)rowf[ra])[h4];
        const float4 r4b = ((const float4*)rowf[rb])[h4];
        #pragma unroll
        for (int j = 0; j < 4; ++j) {
            const float w = W[(size_t)(h4 * 4 + j) * HA + a];
            a0 = fmaf(((const float*)&r4a)[j], w, a0);
            a1 = fmaf(((const float*)&r4b)[j], w, a1);
        }
    }
    const float bb = bs[a];
    const float e0 = __builtin_amdgcn_exp2f((a0 + bb) * KSC);
    const float e1 = __builtin_amdgcn_exp2f((a1 + bb) * KSC);
    if (is_q) {
        const int r = r0 - NB * SKV;
        eq[(size_t)(r + ra) * HA + a] = e0;
        eq[(size_t)(r + rb) * HA + a] = e1;
    } else {
        const int bI = r0 >> 10, s0 = r0 & 1023;
        float* __restrict__ p =
            ekT + ((size_t)(bI * 32 + (a >> 2)) * SKV + s0) * 4 + (a & 3);
        p[(size_t)ra * 4] = e0;
        p[(size_t)rb * 4] = e1;
    }
}

// ---------------- Kernel B: scores + softmax + weight write ----------------
// one block = 4 (b,q) rows; 1024 threads; grid 256.
// REGISTER-Q / a-sliced: lane = (a_sl = lane>>3) x (s_sub = lane&7).
// Each thread holds Q[4q][16a] + wv[16a] in VGPRs (loaded once); hot loop has
// ZERO LDS reads — 4 coalesced E b128 + 192 VALU per k, then 3x shfl_xor
// butterfly over the 8 a-slices.  Scores staged to a small LDS buffer for the
// block softmax.
__global__ __launch_bounds__(1024) void attn_kernel(
    const float* __restrict__ ekT,         // (b,32,1024,4) interleaved exps
    const float* __restrict__ eq,          // (1024,128) exps, row-major
    const float* __restrict__ wv,          // (128)
    float* __restrict__ out)               // [262144 out0][1048576 weights]
{
    __shared__ __align__(16) float4 sc_s[SKV];    // 16 KB: (t0,t1,t2,t3) per s
    __shared__ float red[2][4][16];

    const int tid  = threadIdx.x;
    const int lane = tid & 63, w = tid >> 6;
    const int s_sub = lane & 7, a_sl = lane >> 3;  // 8 s x 8 a-slices
    const int bq0  = blockIdx.x * 4;       // never straddles b (512%4==0)
    const int b    = bq0 >> 9;

    // ---- one-time register loads: Q-slice (4q x 4 f4) + wv-slice (4 f4) ----
    const float4* __restrict__ eq4 = (const float4*)eq;
    const float4* __restrict__ wv4 = (const float4*)wv;
    float4 Qr[4][4], wr[4];
    #pragma unroll
    for (int j = 0; j < 4; ++j) {
        wr[j] = wv4[a_sl * 4 + j];
        #pragma unroll
        for (int q = 0; q < 4; ++q)
            Qr[q][j] = eq4[(size_t)(bq0 + q) * 32 + a_sl * 4 + j];
    }

    const float4* __restrict__ E4 = (const float4*)ekT + (size_t)b * 32 * SKV;

    // ---- k-loop: 8 s per (wave,k); partial over 16 a's; butterfly over a_sl ----
    #pragma unroll 2
    for (int k = 0; k < 8; ++k) {
        const int s = w * 64 + k * 8 + s_sub;
        float4 E[4];
        #pragma unroll
        for (int j = 0; j < 4; ++j)
            E[j] = E4[(size_t)(a_sl * 4 + j) * SKV + s];   // 128B/line per slice

        float p[4] = {0.f, 0.f, 0.f, 0.f};
        #pragma unroll
        for (int j = 0; j < 4; ++j) {
            #pragma unroll
            for (int q = 0; q < 4; ++q) {
                float u  = fmaf(E[j].x, Qr[q][j].x, 1.f);
                float v  = fmaf(E[j].y, Qr[q][j].y, 1.f);
                p[q] = fmaf(fmaf(wr[j].x, v, wr[j].y * u),
                            __builtin_amdgcn_rcpf(u * v), p[q]);
                float u2 = fmaf(E[j].z, Qr[q][j].z, 1.f);
                float v2 = fmaf(E[j].w, Qr[q][j].w, 1.f);
                p[q] = fmaf(fmaf(wr[j].z, v2, wr[j].w * u2),
                            __builtin_amdgcn_rcpf(u2 * v2), p[q]);
            }
        }
        // reduce over the 8 a-slices (lanes stride-8): butterfly, all lanes get sum
        #pragma unroll
        for (int q = 0; q < 4; ++q) {
            p[q] += __shfl_xor(p[q], 8);
            p[q] += __shfl_xor(p[q], 16);
            p[q] += __shfl_xor(p[q], 32);
        }
        if (a_sl == 0)                     // lanes 0..7: 8 consecutive float4
            sc_s[s] = make_float4(p[0], p[1], p[2], p[3]);
    }
    __syncthreads();

    // ---- softmax over s (thread = one s).  weight ∝ exp(-2*(t - tmin)) ----
    const float4 tv = sc_s[tid];
    float tq[4] = {tv.x, tv.y, tv.z, tv.w};
    const int wid = w;
    #pragma unroll
    for (int q = 0; q < 4; ++q) {
        float m = tq[q];
        #pragma unroll
        for (int o = 32; o > 0; o >>= 1) m = fminf(m, __shfl_down(m, o));
        if (lane == 0) red[0][q][wid] = m;
    }
    __syncthreads();
    float M[4];
    #pragma unroll
    for (int q = 0; q < 4; ++q) {
        float m = red[0][q][0];
        #pragma unroll
        for (int i = 1; i < 16; ++i) m = fminf(m, red[0][q][i]);
        M[q] = m;
    }
    float e[4];
    #pragma unroll
    for (int q = 0; q < 4; ++q) {
        e[q] = __builtin_amdgcn_exp2f((M[q] - tq[q]) * KSC);   // exp(-2(t-tmin))
        float sum = e[q];
        #pragma unroll
        for (int o = 32; o > 0; o >>= 1) sum += __shfl_down(sum, o);
        if (lane == 0) red[1][q][wid] = sum;
    }
    __syncthreads();
    float* __restrict__ outw = out + (size_t)NB * NSQ * HIN;   // weights at 262144
    #pragma unroll
    for (int q = 0; q < 4; ++q) {
        float d = red[1][q][0];
        #pragma unroll
        for (int i = 1; i < 16; ++i) d += red[1][q][i];
        outw[(size_t)(bq0 + q) * SKV + tid] = e[q] * __builtin_amdgcn_rcpf(d);
    }
}

// ---------------- Kernel C: out0 = weights @ kv ----------------
// (R2 version, unchanged — part of the best measured build.)
__global__ __launch_bounds__(512) void out_kernel(
    const float* __restrict__ kv,          // (2048,256)
    const float* __restrict__ outw,        // (1024,1024) weights (just written)
    float* __restrict__ out)               // out0 (1024,256)
{
    __shared__ __align__(16) float wtT[SKV][8];        // 32 KB
    __shared__ __align__(16) float part[16][8][HA];    // 64 KB

    const int t  = threadIdx.x;
    const int qg = blockIdx.x >> 1, hh = blockIdx.x & 1;
    const int b  = qg >> 6;                // 64 q-groups per batch

    #pragma unroll
    for (int j = 0; j < 16; ++j) {
        const int idx = j * 512 + t, q = idx >> 10, s = idx & 1023;
        wtT[s][q] = outw[(size_t)(qg * 8 + q) * SKV + s];
    }
    __syncthreads();

    const int h4 = t & 31, sg = t >> 5;    // 32 float4-of-h x 16 s-groups
    const float4* __restrict__ kv4 =
        (const float4*)kv + ((size_t)(b * SKV + sg * 64)) * 64 + hh * 32 + h4;

    float4 ac[8];
    #pragma unroll
    for (int q = 0; q < 8; ++q) ac[q] = make_float4(0.f, 0.f, 0.f, 0.f);

    #pragma unroll 2
    for (int i = 0; i < 64; ++i) {
        const int s = sg * 64 + i;
        const float4 v  = kv4[(size_t)i * 64];
        const float4 wA = ((const float4*)wtT[s])[0];
        const float4 wB = ((const float4*)wtT[s])[1];
        #pragma unroll
        for (int q = 0; q < 4; ++q) {
            const float wa = ((const float*)&wA)[q];
            ac[q].x = fmaf(wa, v.x, ac[q].x); ac[q].y = fmaf(wa, v.y, ac[q].y);
            ac[q].z = fmaf(wa, v.z, ac[q].z); ac[q].w = fmaf(wa, v.w, ac[q].w);
            const float wb = ((const float*)&wB)[q];
            ac[q+4].x = fmaf(wb, v.x, ac[q+4].x); ac[q+4].y = fmaf(wb, v.y, ac[q+4].y);
            ac[q+4].z = fmaf(wb, v.z, ac[q+4].z); ac[q+4].w = fmaf(wb, v.w, ac[q+4].w);
        }
    }
    #pragma unroll
    for (int q = 0; q < 8; ++q) ((float4*)part[sg][q])[h4] = ac[q];
    __syncthreads();

    #pragma unroll
    for (int k = 0; k < 2; ++k) {
        const int idx = k * 512 + t, q = idx >> 7, h = idx & 127;
        float v = 0.f;
        #pragma unroll
        for (int g = 0; g < 16; ++g) v += part[g][q][h];
        out[(size_t)(qg * 8 + q) * HIN + hh * HA + h] = v;
    }
}

extern "C" void kernel_launch(void* const* d_in, const int* in_sizes, int n_in,
                              void* d_out, int out_size, void* d_ws, size_t ws_size,
                              hipStream_t stream) {
    (void)in_sizes; (void)n_in; (void)out_size; (void)ws_size;
    const float* kv  = (const float*)d_in[0];
    const float* qy  = (const float*)d_in[1];
    const float* Wkv = (const float*)d_in[2];
    const float* bkv = (const float*)d_in[3];
    const float* Wq  = (const float*)d_in[4];
    const float* bq  = (const float*)d_in[5];
    const float* wv  = (const float*)d_in[6];
    float* ekT = (float*)d_ws;                 // 1 MB
    float* eqp = ekT + (size_t)NB * SKV * HA;  // 0.5 MB
    float* out = (float*)d_out;
    float* outw = out + (size_t)NB * NSQ * HIN;

    hipLaunchKernelGGL(proj_kernel, dim3((NB * SKV + NB * NSQ) / 8), dim3(512), 0, stream,
                       kv, qy, Wkv, bkv, Wq, bq, ekT, eqp);
    hipLaunchKernelGGL(attn_kernel, dim3(NB * NSQ / 4), dim3(1024), 0, stream,
                       ekT, eqp, wv, out);
    hipLaunchKernelGGL(out_kernel, dim3(NB * NSQ / 4), dim3(512), 0, stream,
                       kv, outw, out);
}

// Round 6
// 108.122 us; speedup vs baseline: 1.1507x; 1.0922x over previous
//
#include <hip/hip_runtime.h>

#define NB   2
#define SKV  1024
#define NSQ  512
#define HIN  256
#define HA   128

// projections pre-scaled by 2*log2(e):  exp2(KSC*x) = e^{2x}
// tanh(x) = 1 - 2/(e^{2x}+1); softmax is shift-invariant so the constant
// W0+bv terms of the score are dropped entirely.
#define KSC   2.8853900817779268f   // 2*log2(e)

// ---------------- Kernel A: projections -> exponentials ----------------
// (R2 version, unchanged — best measured build.)
// kv rows -> ekT, INTERLEAVED-TRANSPOSED: ekT[b][a>>2][s][a&3]; q rows -> eq
// row-major [r][a].
__global__ __launch_bounds__(512) void proj_kernel(
    const float* __restrict__ kv,
    const float* __restrict__ qy,
    const float* __restrict__ Wkv,
    const float* __restrict__ bkv,
    const float* __restrict__ Wq,
    const float* __restrict__ bq,
    float* __restrict__ ekT,
    float* __restrict__ eq)
{
    __shared__ __align__(16) float rowf[8][HIN];
    const int t  = threadIdx.x;
    const int a  = t & 127;            // output channel
    const int rh = t >> 7;             // row-pair id (0..3)
    const int r0 = blockIdx.x * 8;     // 8 rows per block
    const bool is_q = (r0 >= NB * SKV);
    const float* __restrict__ src = is_q ? (qy + (size_t)(r0 - NB * SKV) * HIN)
                                         : (kv + (size_t)r0 * HIN);
    const float* __restrict__ W  = is_q ? Wq : Wkv;
    const float* __restrict__ bs = is_q ? bq : bkv;

    ((float4*)rowf)[t] = ((const float4*)src)[t];
    __syncthreads();

    float a0 = 0.f, a1 = 0.f;
    const int ra = rh * 2, rb = rh * 2 + 1;
    #pragma unroll 4
    for (int h4 = 0; h4 < 64; ++h4) {
        const float4 r4a = ((const float4*)rowf[ra])[h4];
        const float4 r4b = ((const float4*)rowf[rb])[h4];
        #pragma unroll
        for (int j = 0; j < 4; ++j) {
            const float w = W[(size_t)(h4 * 4 + j) * HA + a];
            a0 = fmaf(((const float*)&r4a)[j], w, a0);
            a1 = fmaf(((const float*)&r4b)[j], w, a1);
        }
    }
    const float bb = bs[a];
    const float e0 = __builtin_amdgcn_exp2f((a0 + bb) * KSC);
    const float e1 = __builtin_amdgcn_exp2f((a1 + bb) * KSC);
    if (is_q) {
        const int r = r0 - NB * SKV;
        eq[(size_t)(r + ra) * HA + a] = e0;
        eq[(size_t)(r + rb) * HA + a] = e1;
    } else {
        const int bI = r0 >> 10, s0 = r0 & 1023;
        float* __restrict__ p =
            ekT + ((size_t)(bI * 32 + (a >> 2)) * SKV + s0) * 4 + (a & 3);
        p[(size_t)ra * 4] = e0;
        p[(size_t)rb * 4] = e1;
    }
}

// ---------------- Kernel B: scores + softmax + weights + output (FUSED) ----
// one block = 4 (b,q) rows; 1024 threads (16 waves); grid 256.
// Phase 2 is the R2-measured-best form (LDS-broadcast Q/wv, coalesced E b128,
// paired rcp).  After softmax, weights stay in LDS and the out-phase
// (out0[q][h] = sum_s w[q][s]*kv[b][s][h]) runs in the same block — no outw
// re-read, no second staging, one less kernel boundary.
__global__ __launch_bounds__(1024) void attn_kernel(
    const float* __restrict__ ekT,         // (b,32,1024,4) interleaved exps
    const float* __restrict__ eq,          // (1024,128) exps, row-major
    const float* __restrict__ wv,          // (128)
    const float* __restrict__ kv,          // (2048,256) f32
    float* __restrict__ out)               // [262144 out0][1048576 weights]
{
    __shared__ __align__(16) float eq_s[4][HA];        // 2 KB
    __shared__ __align__(16) float wv_s[HA];           // 0.5 KB
    __shared__ __align__(16) float wt_s[SKV][4];       // 16 KB
    __shared__ __align__(16) float part[16][4][HIN];   // 64 KB
    __shared__ float red[2][4][16];

    const int tid  = threadIdx.x;
    const int lane = tid & 63, wid = tid >> 6;
    const int bq0  = blockIdx.x * 4;       // never straddles b (512%4==0)
    const int b    = bq0 >> 9;

    if (tid < 512) ((float*)eq_s)[tid] = eq[(size_t)bq0 * HA + tid];
    else if (tid < 640) wv_s[tid - 512] = wv[tid - 512];
    __syncthreads();

    // ---- phase 2: per-thread s, 4 q accumulators; paired rcp over a ----
    const float4* __restrict__ E4 =
        (const float4*)ekT + (size_t)b * 32 * SKV + tid;   // + a4*SKV per iter
    float t0 = 0.f, t1 = 0.f, t2 = 0.f, t3 = 0.f;

    #pragma unroll 4
    for (int a4 = 0; a4 < 32; ++a4) {
        const float4 E = E4[(size_t)a4 * SKV];             // coalesced b128
        const float4 w = ((const float4*)wv_s)[a4];        // LDS broadcast

#define PQ(ACC, QI)                                                           \
        {                                                                     \
            const float4 Q = ((const float4*)eq_s[QI])[a4];  /* broadcast */  \
            float u  = fmaf(E.x, Q.x, 1.f);                                   \
            float v  = fmaf(E.y, Q.y, 1.f);                                   \
            ACC = fmaf(fmaf(w.x, v, w.y * u),                                 \
                       __builtin_amdgcn_rcpf(u * v), ACC);                    \
            float u2 = fmaf(E.z, Q.z, 1.f);                                   \
            float v2 = fmaf(E.w, Q.w, 1.f);                                   \
            ACC = fmaf(fmaf(w.z, v2, w.w * u2),                               \
                       __builtin_amdgcn_rcpf(u2 * v2), ACC);                  \
        }
        PQ(t0, 0) PQ(t1, 1) PQ(t2, 2) PQ(t3, 3)
#undef PQ
    }

    // ---- phase 3: softmax over s.  weight ∝ exp(-2*(t - tmin)) ----
    float tq[4] = {t0, t1, t2, t3};
    #pragma unroll
    for (int q = 0; q < 4; ++q) {
        float m = tq[q];
        #pragma unroll
        for (int o = 32; o > 0; o >>= 1) m = fminf(m, __shfl_down(m, o));
        if (lane == 0) red[0][q][wid] = m;
    }
    __syncthreads();
    float M[4];
    #pragma unroll
    for (int q = 0; q < 4; ++q) {
        float m = red[0][q][0];
        #pragma unroll
        for (int i = 1; i < 16; ++i) m = fminf(m, red[0][q][i]);
        M[q] = m;
    }
    float e[4];
    #pragma unroll
    for (int q = 0; q < 4; ++q) {
        e[q] = __builtin_amdgcn_exp2f((M[q] - tq[q]) * KSC);   // exp(-2(t-tmin))
        float sum = e[q];
        #pragma unroll
        for (int o = 32; o > 0; o >>= 1) sum += __shfl_down(sum, o);
        if (lane == 0) red[1][q][wid] = sum;
    }
    __syncthreads();
    float* __restrict__ outw = out + (size_t)NB * NSQ * HIN;   // weights at 262144
    float wgt[4];
    #pragma unroll
    for (int q = 0; q < 4; ++q) {
        float d = red[1][q][0];
        #pragma unroll
        for (int i = 1; i < 16; ++i) d += red[1][q][i];
        wgt[q] = e[q] * __builtin_amdgcn_rcpf(d);
        outw[(size_t)(bq0 + q) * SKV + tid] = wgt[q];          // coalesced per q
    }
    *(float4*)&wt_s[tid][0] = make_float4(wgt[0], wgt[1], wgt[2], wgt[3]);
    __syncthreads();

    // ---- phase 4: out[q][h] = sum_s w[q][s]*kv[b][s][h] ----
    // wave g handles s in [g*64, g*64+64); lane = float4 chunk of h (64*16B=256f)
    {
        const int g = wid;                 // 0..15
        float4 ac0 = {0,0,0,0}, ac1 = {0,0,0,0}, ac2 = {0,0,0,0}, ac3 = {0,0,0,0};
        const float4* __restrict__ kvb =
            (const float4*)kv + (size_t)(b * SKV + g * 64) * 64;
        #pragma unroll 4
        for (int i = 0; i < 64; ++i) {
            const float4 w4 = *((const float4*)&wt_s[g * 64 + i][0]); // broadcast
            const float4 v  = kvb[(size_t)i * 64 + lane];             // 1KB/wave
            ac0.x = fmaf(w4.x, v.x, ac0.x); ac0.y = fmaf(w4.x, v.y, ac0.y);
            ac0.z = fmaf(w4.x, v.z, ac0.z); ac0.w = fmaf(w4.x, v.w, ac0.w);
            ac1.x = fmaf(w4.y, v.x, ac1.x); ac1.y = fmaf(w4.y, v.y, ac1.y);
            ac1.z = fmaf(w4.y, v.z, ac1.z); ac1.w = fmaf(w4.y, v.w, ac1.w);
            ac2.x = fmaf(w4.z, v.x, ac2.x); ac2.y = fmaf(w4.z, v.y, ac2.y);
            ac2.z = fmaf(w4.z, v.z, ac2.z); ac2.w = fmaf(w4.z, v.w, ac2.w);
            ac3.x = fmaf(w4.w, v.x, ac3.x); ac3.y = fmaf(w4.w, v.y, ac3.y);
            ac3.z = fmaf(w4.w, v.z, ac3.z); ac3.w = fmaf(w4.w, v.w, ac3.w);
        }
        ((float4*)part[g][0])[lane] = ac0;
        ((float4*)part[g][1])[lane] = ac1;
        ((float4*)part[g][2])[lane] = ac2;
        ((float4*)part[g][3])[lane] = ac3;
    }
    __syncthreads();
    {
        const int q = tid >> 8, h = tid & 255;       // 1024 outputs, 1/thread
        float v = 0.f;
        #pragma unroll
        for (int g2 = 0; g2 < 16; ++g2) v += part[g2][q][h];   // stride-1 banks
        out[(size_t)(bq0 + q) * HIN + h] = v;        // coalesced
    }
}

extern "C" void kernel_launch(void* const* d_in, const int* in_sizes, int n_in,
                              void* d_out, int out_size, void* d_ws, size_t ws_size,
                              hipStream_t stream) {
    (void)in_sizes; (void)n_in; (void)out_size; (void)ws_size;
    const float* kv  = (const float*)d_in[0];
    const float* qy  = (const float*)d_in[1];
    const float* Wkv = (const float*)d_in[2];
    const float* bkv = (const float*)d_in[3];
    const float* Wq  = (const float*)d_in[4];
    const float* bq  = (const float*)d_in[5];
    const float* wv  = (const float*)d_in[6];
    float* ekT = (float*)d_ws;                 // 1 MB
    float* eqp = ekT + (size_t)NB * SKV * HA;  // 0.5 MB
    float* out = (float*)d_out;

    hipLaunchKernelGGL(proj_kernel, dim3((NB * SKV + NB * NSQ) / 8), dim3(512), 0, stream,
                       kv, qy, Wkv, bkv, Wq, bq, ekT, eqp);
    hipLaunchKernelGGL(attn_kernel, dim3(NB * NSQ / 4), dim3(1024), 0, stream,
                       ekT, eqp, wv, kv, out);
}